// Round 7
// baseline (219.412 us; speedup 1.0000x reference)
//
#include <hip/hip_runtime.h>
#include <hip/hip_bf16.h>
#include <cstdint>

// bf16 fragments as 8 x short (4 VGPRs) per cdna_hip_programming.md §3
typedef __attribute__((ext_vector_type(8))) short bf16x8;
typedef __attribute__((ext_vector_type(4))) float f32x4;
typedef __attribute__((ext_vector_type(4))) uint16_t u16x4;

__device__ __forceinline__ uint16_t f2b(float f) {
  union { float f; uint32_t i; } v; v.f = f;
  return (uint16_t)((v.i + 0x7FFFu + ((v.i >> 16) & 1u)) >> 16);  // RNE
}

// async global->LDS, 16B per lane; LDS dest is wave-uniform base + lane*16
#define GLDS16(g, l) __builtin_amdgcn_global_load_lds( \
    (const __attribute__((address_space(1))) void*)(g), \
    (__attribute__((address_space(3))) void*)(l), 16, 0, 0)

// ---------------------------------------------------------------------------
// fp32 -> bf16 convert (RNE) for all three inputs in one launch
// ---------------------------------------------------------------------------
__global__ __launch_bounds__(256) void cvt_all(
    const float* __restrict__ x, const float* __restrict__ wa, const float* __restrict__ wp,
    uint16_t* __restrict__ xb, uint16_t* __restrict__ wab, uint16_t* __restrict__ wpb) {
  const int i = (blockIdx.x * 256 + threadIdx.x) * 4;
  const float* src; uint16_t* dst; int off;
  if (i < 4194304)      { src = x;  dst = xb;  off = i; }
  else if (i < 7340032) { src = wa; dst = wab; off = i - 4194304; }
  else                  { src = wp; dst = wpb; off = i - 7340032; }
  const float4 v = *(const float4*)(src + off);
  u16x4 o;
  o.x = f2b(v.x); o.y = f2b(v.y); o.z = f2b(v.z); o.w = f2b(v.w);
  *(u16x4*)(dst + off) = o;
}

// ---------------------------------------------------------------------------
// C[M,N] = A[M,K] @ B[N,K]^T + bias[N]. A,B bf16, bias fp32, fp32 accumulate.
// m97-proven BK=32 single-stage loop; BM x 128 tile, 4 waves of (BM/2) x 64.
// Vectorized epilogue via per-wave LDS transpose.
// ---------------------------------------------------------------------------
template <int BM, bool OUT_BF16>
__global__ __launch_bounds__(256) void gemm_bt_bias(
    const uint16_t* __restrict__ A, const uint16_t* __restrict__ B,
    const float* __restrict__ bias, void* __restrict__ Cv,
    int M, int N, int K) {
  constexpr int MI = BM / 32;            // acc rows of 16 per wave
  constexpr int CHA = BM / 16;           // A staging chunks (16 rows each)
  constexpr int CPW = (CHA + 8) / 4;     // chunks per wave
  constexpr size_t ST_BYTES = (size_t)(BM + 128) * 32 * 2;
  constexpr size_t CT_BYTES = OUT_BF16 ? (size_t)4 * (BM / 2) * 72 * 2
                                       : (size_t)4 * (BM / 2) * 68 * 4;
  constexpr size_t LB = CT_BYTES > ST_BYTES ? CT_BYTES : ST_BYTES;
  __shared__ alignas(16) unsigned char ldsb[LB];
  uint16_t* lds = (uint16_t*)ldsb;
  const int offB = BM * 32;

  const int tid = threadIdx.x;
  const int wave = tid >> 6, lane = tid & 63;
  const int q4 = lane >> 4, l16 = lane & 15;
  const int wm = wave >> 1, wn = wave & 1;
  const long blockM = (long)blockIdx.y * BM;
  const long blockN = (long)blockIdx.x * 128;

  f32x4 acc[MI][4] = {};

  for (int k0 = 0; k0 < K; k0 += 32) {
#pragma unroll
    for (int c = 0; c < CPW; ++c) {
      const int id = c * 4 + wave;       // wave-uniform
      const bool isB = id >= CHA;
      const int a = isB ? id - CHA : id;
      const uint16_t* mat = isB ? B : A;
      const long rowBase = isB ? blockN : blockM;
      const int off = isB ? offB : 0;
      const int flat = a * 64 + lane;
      const int row = flat >> 2, seg = flat & 3;
      GLDS16(mat + (rowBase + row) * (long)K + k0 + seg * 8, lds + off + a * 512);
    }
    __syncthreads();
    bf16x8 af[MI], bfr[4];
#pragma unroll
    for (int i = 0; i < MI; ++i)
      af[i] = *(const bf16x8*)&lds[(wm * (BM / 2) + i * 16 + l16) * 32 + q4 * 8];
#pragma unroll
    for (int j = 0; j < 4; ++j)
      bfr[j] = *(const bf16x8*)&lds[offB + (wn * 64 + j * 16 + l16) * 32 + q4 * 8];
#pragma unroll
    for (int i = 0; i < MI; ++i)
#pragma unroll
      for (int j = 0; j < 4; ++j)
        acc[i][j] = __builtin_amdgcn_mfma_f32_16x16x32_bf16(af[i], bfr[j], acc[i][j], 0, 0, 0);
    __syncthreads();
  }

  // epilogue: acc (C/D layout: col=l16, row=q4*4+r) -> per-wave LDS tile -> vector stores
  if (OUT_BF16) {
    uint16_t* ct = lds + wave * (BM / 2) * 72;
#pragma unroll
    for (int j = 0; j < 4; ++j) {
      const float bv = bias[blockN + wn * 64 + j * 16 + l16];
#pragma unroll
      for (int i = 0; i < MI; ++i)
#pragma unroll
        for (int r = 0; r < 4; ++r)
          ct[(i * 16 + q4 * 4 + r) * 72 + j * 16 + l16] = f2b(acc[i][j][r] + bv);
    }
    __syncthreads();
    uint16_t* Cb = (uint16_t*)Cv;
#pragma unroll
    for (int st = 0; st < BM / 16; ++st) {
      const int flat = st * 64 + lane;
      const int row = flat >> 3, seg = flat & 7;
      const bf16x8 v = *(const bf16x8*)&ct[row * 72 + seg * 8];
      *(bf16x8*)&Cb[(blockM + wm * (BM / 2) + row) * (long)N + blockN + wn * 64 + seg * 8] = v;
    }
  } else {
    float* ct = (float*)ldsb + wave * (BM / 2) * 68;
#pragma unroll
    for (int j = 0; j < 4; ++j) {
      const float bv = bias[blockN + wn * 64 + j * 16 + l16];
#pragma unroll
      for (int i = 0; i < MI; ++i)
#pragma unroll
        for (int r = 0; r < 4; ++r)
          ct[(i * 16 + q4 * 4 + r) * 68 + j * 16 + l16] = acc[i][j][r] + bv;
    }
    __syncthreads();
    float* Cb = (float*)Cv;
#pragma unroll
    for (int st = 0; st < BM / 8; ++st) {
      const int flat = st * 64 + lane;
      const int row = flat >> 4, seg = flat & 15;
      const f32x4 v = *(const f32x4*)&ct[row * 68 + seg * 4];
      *(f32x4*)&Cb[(blockM + wm * (BM / 2) + row) * (long)N + blockN + wn * 64 + seg * 4] = v;
    }
  }
}

// ---------------------------------------------------------------------------
// Flash-style causal attention, S^T formulation, software-pipelined:
// one barrier per K-tile, K/V prefetched into VGPRs with loads issued AFTER
// the barrier (never crossing one -> no vmcnt(0) drain of prefetch).
// Tile loop flattened over both paired strips (31-p then p): 17 tiles/block.
// Grid 512 = 2 blocks/CU steady. V,P double-buffered in LDS.
// ---------------------------------------------------------------------------
__global__ __launch_bounds__(256, 2) void attn_flash(
    const uint16_t* __restrict__ kqv, uint16_t* __restrict__ attn) {
  constexpr int T = 2048, C = 1024, C3 = 3072;
  __shared__ alignas(16) uint16_t Vt[2][64 * 136];  // V^T [d][key'], key'=(key+16*(d>>3))&127
  __shared__ alignas(16) uint16_t Pt[2][4 * 2176];  // per wave 16 x 136

  const int tid = threadIdx.x;
  const int wave = tid >> 6, lane = tid & 63;
  const int q4 = lane >> 4, l16 = lane & 15;
  const int p = blockIdx.x >> 5, bh = blockIdx.x & 31;
  const int b = bh >> 4, h = bh & 15;
  const size_t base = (size_t)b * T * C3;
  const size_t obase = (size_t)b * T * C;
  const int hD = h * 64;
  const float sc = 0.125f * 1.4426950408889634f;  // D^-0.5 * log2(e)

  const int qb0 = 31 - p, qb1 = p;
  const int nkt0 = (qb0 >> 1) + 1;                // strip-0 tiles; total always 17
  const int tr = tid >> 3, kch = tid & 7;         // V-staging coords

  int qb = qb0;
  int qrow = qb * 64 + wave * 16 + l16;
  bf16x8 qf0 = *(const bf16x8*)&kqv[base + (size_t)qrow * C3 + C + hD + q4 * 8];
  bf16x8 qf1 = *(const bf16x8*)&kqv[base + (size_t)qrow * C3 + C + hD + 32 + q4 * 8];

  f32x4 o[4] = {};
  float m_i = -1e30f, l_i = 0.f;
  int cb = 0, kt = 0;
  bool ss1 = false;

  // prefetch tile 0 (keys 0..127 — identical for every strip)
  bf16x8 pk[8][2], pv[2][2];
#pragma unroll
  for (int nk = 0; nk < 8; ++nk) {
    const uint16_t* kr = &kqv[base + (size_t)(nk * 16 + l16) * C3 + hD + q4 * 8];
    pk[nk][0] = *(const bf16x8*)kr;
    pk[nk][1] = *(const bf16x8*)(kr + 32);
  }
#pragma unroll
  for (int s2 = 0; s2 < 2; ++s2) {
    const size_t g = base + (size_t)(2 * (s2 * 32 + tr)) * C3 + 2 * C + hD + kch * 8;
    pv[s2][0] = *(const bf16x8*)&kqv[g];
    pv[s2][1] = *(const bf16x8*)&kqv[g + C3];
  }

  for (int t = 0; t < 17; ++t) {
    const int kbase = kt * 128;
    const bool lastOfStrip = !ss1 ? (kt == nkt0 - 1) : (t == 16);
    const int knext = lastOfStrip ? 0 : kt + 1;

    // --- QK(t) from prefetched regs: lane holds S^T[key=16nk+q4*4+r][q=l16] ---
    f32x4 s[8];
#pragma unroll
    for (int nk = 0; nk < 8; ++nk) {
      f32x4 z = {};
      z = __builtin_amdgcn_mfma_f32_16x16x32_bf16(pk[nk][0], qf0, z, 0, 0, 0);
      z = __builtin_amdgcn_mfma_f32_16x16x32_bf16(pk[nk][1], qf1, z, 0, 0, 0);
      s[nk] = z;
    }
    // causal mask only on diagonal tiles (wave-uniform branch)
    if (kbase + 127 > qb * 64 + wave * 16) {
#pragma unroll
      for (int nk = 0; nk < 8; ++nk) {
        const int key0 = kbase + nk * 16 + q4 * 4;
#pragma unroll
        for (int r = 0; r < 4; ++r)
          s[nk][r] = (key0 + r <= qrow) ? s[nk][r] : -1e30f;
      }
    }
    // --- online softmax (per-lane over 32 keys + 2 shuffles) ---
    float mloc = s[0][0];
#pragma unroll
    for (int nk = 0; nk < 8; ++nk)
#pragma unroll
      for (int r = 0; r < 4; ++r) mloc = fmaxf(mloc, s[nk][r]);
    mloc = fmaxf(mloc, __shfl_xor(mloc, 16, 64));
    mloc = fmaxf(mloc, __shfl_xor(mloc, 32, 64));
    const float mnew = fmaxf(m_i, mloc * sc);
    const float alpha = exp2f(m_i - mnew);
    const bool mchg = mnew > m_i;
    m_i = mnew;
    float rs = 0.f;
#pragma unroll
    for (int nk = 0; nk < 8; ++nk)
#pragma unroll
      for (int r = 0; r < 4; ++r) {
        const float pe = exp2f(fmaf(s[nk][r], sc, -mnew));
        s[nk][r] = pe;
        rs += pe;
      }
    rs += __shfl_xor(rs, 16, 64);
    rs += __shfl_xor(rs, 32, 64);
    l_i = l_i * alpha + rs;
    if (__any(mchg)) {
#pragma unroll
      for (int r = 0; r < 4; ++r) {
        const float ar = __shfl(alpha, q4 * 4 + r, 64);
#pragma unroll
        for (int d4 = 0; d4 < 4; ++d4) o[d4][r] *= ar;
      }
    }
    // --- stage V(t) from regs -> Vt[cb] (v_perm pack, rot-16 swizzle) ---
    {
      uint32_t* VtW = (uint32_t*)Vt[cb];   // pitch 68 dwords
#pragma unroll
      for (int s2 = 0; s2 < 2; ++s2) {
        const int colw = ((s2 * 32 + tr) + 8 * kch) & 63;
        const uint32_t* a0 = (const uint32_t*)&pv[s2][0];
        const uint32_t* a1 = (const uint32_t*)&pv[s2][1];
#pragma unroll
        for (int i = 0; i < 8; ++i) {
          const uint32_t w = (i & 1)
              ? __builtin_amdgcn_perm(a1[i >> 1], a0[i >> 1], 0x07060302u)
              : __builtin_amdgcn_perm(a1[i >> 1], a0[i >> 1], 0x05040100u);
          VtW[(kch * 8 + i) * 68 + colw] = w;
        }
      }
    }
    // --- stage P(t) -> Pt[cb] (packed bf16 pairs, one b64 per nk) ---
    uint16_t* Pw = &Pt[cb][wave * 2176];
#pragma unroll
    for (int nk = 0; nk < 8; ++nk) {
      union { __hip_bfloat162 h2; uint32_t u; } c01, c23;
      c01.h2 = __float22bfloat162_rn(make_float2(s[nk][0], s[nk][1]));
      c23.h2 = __float22bfloat162_rn(make_float2(s[nk][2], s[nk][3]));
      uint2 pkw; pkw.x = c01.u; pkw.y = c23.u;
      *(uint2*)&Pw[l16 * 136 + nk * 16 + q4 * 4] = pkw;
    }
    __syncthreads();   // the ONLY barrier; no prefetch outstanding here
    // --- prefetch tile t+1 (issued after barrier, consumed before the next) ---
    if (t < 16) {
      const int kb2 = knext * 128;
#pragma unroll
      for (int nk = 0; nk < 8; ++nk) {
        const uint16_t* kr = &kqv[base + (size_t)(kb2 + nk * 16 + l16) * C3 + hD + q4 * 8];
        pk[nk][0] = *(const bf16x8*)kr;
        pk[nk][1] = *(const bf16x8*)(kr + 32);
      }
#pragma unroll
      for (int s2 = 0; s2 < 2; ++s2) {
        const size_t g = base + (size_t)(kb2 + 2 * (s2 * 32 + tr)) * C3 + 2 * C + hD + kch * 8;
        pv[s2][0] = *(const bf16x8*)&kqv[g];
        pv[s2][1] = *(const bf16x8*)&kqv[g + C3];
      }
    }
    // --- O += P·V from LDS[cb] ---
#pragma unroll
    for (int ks = 0; ks < 4; ++ks) {
      const bf16x8 pf = *(const bf16x8*)&Pw[l16 * 136 + ks * 32 + q4 * 8];
#pragma unroll
      for (int d4 = 0; d4 < 4; ++d4) {
        const int d = d4 * 16 + l16;
        const int col = (ks * 32 + q4 * 8 + 16 * (d >> 3)) & 127;
        const bf16x8 vf = *(const bf16x8*)&Vt[cb][d * 136 + col];
        o[d4] = __builtin_amdgcn_mfma_f32_16x16x32_bf16(pf, vf, o[d4], 0, 0, 0);
      }
    }
    // --- strip boundary: write O, reset state, switch to strip 1 ---
    if (lastOfStrip) {
      const float linv = 1.0f / l_i;
#pragma unroll
      for (int r = 0; r < 4; ++r) {
        const float lr = __shfl(linv, q4 * 4 + r, 64);
        const int q = qb * 64 + wave * 16 + q4 * 4 + r;
        const size_t rowoff = obase + (size_t)q * C + hD;
#pragma unroll
        for (int d4 = 0; d4 < 4; ++d4)
          attn[rowoff + d4 * 16 + l16] = f2b(o[d4][r] * lr);
      }
      if (!ss1) {
        ss1 = true;
        qb = qb1;
        qrow = qb * 64 + wave * 16 + l16;
        qf0 = *(const bf16x8*)&kqv[base + (size_t)qrow * C3 + C + hD + q4 * 8];
        qf1 = *(const bf16x8*)&kqv[base + (size_t)qrow * C3 + C + hD + 32 + q4 * 8];
#pragma unroll
        for (int d4 = 0; d4 < 4; ++d4) o[d4] = (f32x4){0.f, 0.f, 0.f, 0.f};
        m_i = -1e30f; l_i = 0.f;
        kt = 0;
      }
    } else {
      ++kt;
    }
    cb ^= 1;
  }
}

extern "C" void kernel_launch(void* const* d_in, const int* in_sizes, int n_in,
                              void* d_out, int out_size, void* d_ws, size_t ws_size,
                              hipStream_t stream) {
  const float* x      = (const float*)d_in[0];  // (2,2048,1024) fp32
  const float* w_attn = (const float*)d_in[1];  // (3072,1024)  fp32
  const float* b_attn = (const float*)d_in[2];  // (3072,)      fp32
  const float* w_proj = (const float*)d_in[3];  // (1024,1024)  fp32
  const float* b_proj = (const float*)d_in[4];  // (1024,)      fp32
  float* out = (float*)d_out;                   // (2,2048,1024) fp32

  // ws layout (bf16): xb | wab | wpb | kqv | attnb
  uint16_t* xb    = (uint16_t*)d_ws;                     // 4096*1024
  uint16_t* wab   = xb  + (size_t)4096 * 1024;           // 3072*1024
  uint16_t* wpb   = wab + (size_t)3072 * 1024;           // 1024*1024
  uint16_t* kqv   = wpb + (size_t)1024 * 1024;           // 4096*3072
  uint16_t* attnb = kqv + (size_t)4096 * 3072;           // 4096*1024

  dim3 blk(256, 1, 1);
  hipLaunchKernelGGL(cvt_all, dim3(8192), blk, 0, stream, x, w_attn, w_proj, xb, wab, wpb);

  hipLaunchKernelGGL((gemm_bt_bias<128, true>), dim3(3072 / 128, 4096 / 128, 1), blk, 0, stream,
                     xb, wab, b_attn, (void*)kqv, 4096, 3072, 1024);
  hipLaunchKernelGGL(attn_flash, dim3(512, 1, 1), blk, 0, stream, kqv, attnb);
  hipLaunchKernelGGL((gemm_bt_bias<64, false>), dim3(1024 / 128, 4096 / 64, 1), blk, 0, stream,
                     attnb, wpb, b_proj, (void*)out, 4096, 1024, 1024);
}

// Round 8
// 198.883 us; speedup vs baseline: 1.1032x; 1.1032x over previous
//
#include <hip/hip_runtime.h>
#include <hip/hip_bf16.h>
#include <cstdint>

// bf16 fragments as 8 x short (4 VGPRs) per cdna_hip_programming.md §3
typedef __attribute__((ext_vector_type(8))) short bf16x8;
typedef __attribute__((ext_vector_type(4))) float f32x4;
typedef __attribute__((ext_vector_type(4))) uint16_t u16x4;

__device__ __forceinline__ uint16_t f2b(float f) {
  union { float f; uint32_t i; } v; v.f = f;
  return (uint16_t)((v.i + 0x7FFFu + ((v.i >> 16) & 1u)) >> 16);  // RNE
}

// async global->LDS, 16B per lane; LDS dest is wave-uniform base + lane*16
#define GLDS16(g, l) __builtin_amdgcn_global_load_lds( \
    (const __attribute__((address_space(1))) void*)(g), \
    (__attribute__((address_space(3))) void*)(l), 16, 0, 0)

// ---------------------------------------------------------------------------
// fp32 -> bf16 convert (RNE) for all three inputs in one launch
// ---------------------------------------------------------------------------
__global__ __launch_bounds__(256) void cvt_all(
    const float* __restrict__ x, const float* __restrict__ wa, const float* __restrict__ wp,
    uint16_t* __restrict__ xb, uint16_t* __restrict__ wab, uint16_t* __restrict__ wpb) {
  const int i = (blockIdx.x * 256 + threadIdx.x) * 4;
  const float* src; uint16_t* dst; int off;
  if (i < 4194304)      { src = x;  dst = xb;  off = i; }
  else if (i < 7340032) { src = wa; dst = wab; off = i - 4194304; }
  else                  { src = wp; dst = wpb; off = i - 7340032; }
  const float4 v = *(const float4*)(src + off);
  u16x4 o;
  o.x = f2b(v.x); o.y = f2b(v.y); o.z = f2b(v.z); o.w = f2b(v.w);
  *(u16x4*)(dst + off) = o;
}

// ---------------------------------------------------------------------------
// C[M,N] = A[M,K] @ B[N,K]^T + bias[N]. A,B bf16, bias fp32, fp32 accumulate.
// m97-proven BK=32 single-stage loop; BM x 128 tile, 4 waves of (BM/2) x 64.
// Vectorized epilogue via per-wave LDS transpose.
// ---------------------------------------------------------------------------
template <int BM, bool OUT_BF16>
__global__ __launch_bounds__(256) void gemm_bt_bias(
    const uint16_t* __restrict__ A, const uint16_t* __restrict__ B,
    const float* __restrict__ bias, void* __restrict__ Cv,
    int M, int N, int K) {
  constexpr int MI = BM / 32;            // acc rows of 16 per wave
  constexpr int CHA = BM / 16;           // A staging chunks (16 rows each)
  constexpr int CPW = (CHA + 8) / 4;     // chunks per wave
  constexpr size_t ST_BYTES = (size_t)(BM + 128) * 32 * 2;
  constexpr size_t CT_BYTES = OUT_BF16 ? (size_t)4 * (BM / 2) * 72 * 2
                                       : (size_t)4 * (BM / 2) * 68 * 4;
  constexpr size_t LB = CT_BYTES > ST_BYTES ? CT_BYTES : ST_BYTES;
  __shared__ alignas(16) unsigned char ldsb[LB];
  uint16_t* lds = (uint16_t*)ldsb;
  const int offB = BM * 32;

  const int tid = threadIdx.x;
  const int wave = tid >> 6, lane = tid & 63;
  const int q4 = lane >> 4, l16 = lane & 15;
  const int wm = wave >> 1, wn = wave & 1;
  const long blockM = (long)blockIdx.y * BM;
  const long blockN = (long)blockIdx.x * 128;

  f32x4 acc[MI][4] = {};

  for (int k0 = 0; k0 < K; k0 += 32) {
#pragma unroll
    for (int c = 0; c < CPW; ++c) {
      const int id = c * 4 + wave;       // wave-uniform
      const bool isB = id >= CHA;
      const int a = isB ? id - CHA : id;
      const uint16_t* mat = isB ? B : A;
      const long rowBase = isB ? blockN : blockM;
      const int off = isB ? offB : 0;
      const int flat = a * 64 + lane;
      const int row = flat >> 2, seg = flat & 3;
      GLDS16(mat + (rowBase + row) * (long)K + k0 + seg * 8, lds + off + a * 512);
    }
    __syncthreads();
    bf16x8 af[MI], bfr[4];
#pragma unroll
    for (int i = 0; i < MI; ++i)
      af[i] = *(const bf16x8*)&lds[(wm * (BM / 2) + i * 16 + l16) * 32 + q4 * 8];
#pragma unroll
    for (int j = 0; j < 4; ++j)
      bfr[j] = *(const bf16x8*)&lds[offB + (wn * 64 + j * 16 + l16) * 32 + q4 * 8];
#pragma unroll
    for (int i = 0; i < MI; ++i)
#pragma unroll
      for (int j = 0; j < 4; ++j)
        acc[i][j] = __builtin_amdgcn_mfma_f32_16x16x32_bf16(af[i], bfr[j], acc[i][j], 0, 0, 0);
    __syncthreads();
  }

  // epilogue: acc (C/D layout: col=l16, row=q4*4+r) -> per-wave LDS tile -> vector stores
  if (OUT_BF16) {
    uint16_t* ct = lds + wave * (BM / 2) * 72;
#pragma unroll
    for (int j = 0; j < 4; ++j) {
      const float bv = bias[blockN + wn * 64 + j * 16 + l16];
#pragma unroll
      for (int i = 0; i < MI; ++i)
#pragma unroll
        for (int r = 0; r < 4; ++r)
          ct[(i * 16 + q4 * 4 + r) * 72 + j * 16 + l16] = f2b(acc[i][j][r] + bv);
    }
    __syncthreads();
    uint16_t* Cb = (uint16_t*)Cv;
#pragma unroll
    for (int st = 0; st < BM / 16; ++st) {
      const int flat = st * 64 + lane;
      const int row = flat >> 3, seg = flat & 7;
      const bf16x8 v = *(const bf16x8*)&ct[row * 72 + seg * 8];
      *(bf16x8*)&Cb[(blockM + wm * (BM / 2) + row) * (long)N + blockN + wn * 64 + seg * 8] = v;
    }
  } else {
    float* ct = (float*)ldsb + wave * (BM / 2) * 68;
#pragma unroll
    for (int j = 0; j < 4; ++j) {
      const float bv = bias[blockN + wn * 64 + j * 16 + l16];
#pragma unroll
      for (int i = 0; i < MI; ++i)
#pragma unroll
        for (int r = 0; r < 4; ++r)
          ct[(i * 16 + q4 * 4 + r) * 68 + j * 16 + l16] = acc[i][j][r] + bv;
    }
    __syncthreads();
    float* Cb = (float*)Cv;
#pragma unroll
    for (int st = 0; st < BM / 8; ++st) {
      const int flat = st * 64 + lane;
      const int row = flat >> 4, seg = flat & 15;
      const f32x4 v = *(const f32x4*)&ct[row * 68 + seg * 4];
      *(f32x4*)&Cb[(blockM + wm * (BM / 2) + row) * (long)N + blockN + wn * 64 + seg * 4] = v;
    }
  }
}

// ---------------------------------------------------------------------------
// Flash-style causal attention, S^T formulation. Two barriers per K-tile:
//   A ; stage K,V (coop, from prefetch regs) ; B ; prefetch(t+1) ; QK ;
//   softmax ; P-write (wave-PRIVATE buffer, no barrier needed) ; PV
// Prefetch crosses only barrier A with a full compute phase in between, so
// the vmcnt drain is free. K,V single-buffered; P in its own region.
// Paired strips (31-p then p): 17 tiles/block; grid 512 = 2 blocks/CU, both
// co-resident blocks identical length. LDS 53 KB.
// ---------------------------------------------------------------------------
__global__ __launch_bounds__(256, 2) void attn_flash(
    const uint16_t* __restrict__ kqv, uint16_t* __restrict__ attn) {
  constexpr int T = 2048, C = 1024, C3 = 3072;
  __shared__ alignas(16) uint16_t Kt[128 * 72];   // K [key][d], pitch 72
  __shared__ alignas(16) uint16_t Vt[64 * 136];   // V^T [d][key'], key'=(key+16*(d>>3))&127
  __shared__ alignas(16) uint16_t Pt[4][16 * 136];// wave-private P
  uint32_t* VtW = (uint32_t*)Vt;                  // pitch 68 dwords

  const int tid = threadIdx.x;
  const int wave = tid >> 6, lane = tid & 63;
  const int q4 = lane >> 4, l16 = lane & 15;
  const int p = blockIdx.x >> 5, bh = blockIdx.x & 31;
  const int b = bh >> 4, h = bh & 15;
  const size_t base = (size_t)b * T * C3;
  const size_t obase = (size_t)b * T * C;
  const int hD = h * 64;
  const float sc = 0.125f * 1.4426950408889634f;  // D^-0.5 * log2(e)

  const int qb0 = 31 - p, qb1 = p;
  const int nkt0 = (qb0 >> 1) + 1;                // strip-0 tiles; strip sum = 17
  const int tr = tid >> 3, kch = tid & 7;         // staging coords

  int qb = qb0;
  int qrow = qb * 64 + wave * 16 + l16;
  bf16x8 qf0 = *(const bf16x8*)&kqv[base + (size_t)qrow * C3 + C + hD + q4 * 8];
  bf16x8 qf1 = *(const bf16x8*)&kqv[base + (size_t)qrow * C3 + C + hD + 32 + q4 * 8];

  f32x4 o[4] = {};
  float m_i = -1e30f, l_i = 0.f;
  int kt = 0;
  bool ss1 = false;

  // prefetch tile 0 (keys 0..127 — identical for every strip)
  bf16x8 pk[4], pv[2][2];
#pragma unroll
  for (int rr = 0; rr < 4; ++rr)
    pk[rr] = *(const bf16x8*)&kqv[base + (size_t)(rr * 32 + tr) * C3 + hD + kch * 8];
#pragma unroll
  for (int s2 = 0; s2 < 2; ++s2) {
    const size_t g = base + (size_t)(2 * (s2 * 32 + tr)) * C3 + 2 * C + hD + kch * 8;
    pv[s2][0] = *(const bf16x8*)&kqv[g];
    pv[s2][1] = *(const bf16x8*)&kqv[g + C3];
  }

  uint16_t* Pw = &Pt[wave][0];

  for (int t = 0; t < 17; ++t) {
    const int kbase = kt * 128;
    const bool lastOfStrip = !ss1 ? (kt == nkt0 - 1) : (t == 16);

    __syncthreads();   // A: prev-tile K/V reads complete; prefetch drains here
    // --- stage K(t): 4 b128 ds_writes per thread ---
#pragma unroll
    for (int rr = 0; rr < 4; ++rr)
      *(bf16x8*)&Kt[(rr * 32 + tr) * 72 + kch * 8] = pk[rr];
    // --- stage V(t): v_perm pack key-pairs, rot-16 swizzle ---
#pragma unroll
    for (int s2 = 0; s2 < 2; ++s2) {
      const int colw = ((s2 * 32 + tr) + 8 * kch) & 63;
      const uint32_t* a0 = (const uint32_t*)&pv[s2][0];
      const uint32_t* a1 = (const uint32_t*)&pv[s2][1];
#pragma unroll
      for (int i = 0; i < 8; ++i) {
        const uint32_t w = (i & 1)
            ? __builtin_amdgcn_perm(a1[i >> 1], a0[i >> 1], 0x07060302u)
            : __builtin_amdgcn_perm(a1[i >> 1], a0[i >> 1], 0x05040100u);
        VtW[(kch * 8 + i) * 68 + colw] = w;
      }
    }
    __syncthreads();   // B: staging visible; no loads outstanding
    // --- prefetch tile t+1 (consumed at stage after next A -> full window) ---
    if (t < 16) {
      const int kb2 = (lastOfStrip ? 0 : kt + 1) * 128;
#pragma unroll
      for (int rr = 0; rr < 4; ++rr)
        pk[rr] = *(const bf16x8*)&kqv[base + (size_t)(kb2 + rr * 32 + tr) * C3 + hD + kch * 8];
#pragma unroll
      for (int s2 = 0; s2 < 2; ++s2) {
        const size_t g = base + (size_t)(kb2 + 2 * (s2 * 32 + tr)) * C3 + 2 * C + hD + kch * 8;
        pv[s2][0] = *(const bf16x8*)&kqv[g];
        pv[s2][1] = *(const bf16x8*)&kqv[g + C3];
      }
    }
    // --- QK(t): S^T = K·Q^T, lane holds S^T[key=16nk+q4*4+r][q=l16] ---
    f32x4 s[8];
#pragma unroll
    for (int nk = 0; nk < 8; ++nk) {
      f32x4 z = {};
      const bf16x8 kf0 = *(const bf16x8*)&Kt[(nk * 16 + l16) * 72 + q4 * 8];
      const bf16x8 kf1 = *(const bf16x8*)&Kt[(nk * 16 + l16) * 72 + 32 + q4 * 8];
      z = __builtin_amdgcn_mfma_f32_16x16x32_bf16(kf0, qf0, z, 0, 0, 0);
      z = __builtin_amdgcn_mfma_f32_16x16x32_bf16(kf1, qf1, z, 0, 0, 0);
      s[nk] = z;
    }
    // causal mask only on diagonal tiles (wave-uniform branch)
    if (kbase + 127 > qb * 64 + wave * 16) {
#pragma unroll
      for (int nk = 0; nk < 8; ++nk) {
        const int key0 = kbase + nk * 16 + q4 * 4;
#pragma unroll
        for (int r = 0; r < 4; ++r)
          s[nk][r] = (key0 + r <= qrow) ? s[nk][r] : -1e30f;
      }
    }
    // --- online softmax (per-lane over 32 keys + 2 shuffles) ---
    float mloc = s[0][0];
#pragma unroll
    for (int nk = 0; nk < 8; ++nk)
#pragma unroll
      for (int r = 0; r < 4; ++r) mloc = fmaxf(mloc, s[nk][r]);
    mloc = fmaxf(mloc, __shfl_xor(mloc, 16, 64));
    mloc = fmaxf(mloc, __shfl_xor(mloc, 32, 64));
    const float mnew = fmaxf(m_i, mloc * sc);
    const float alpha = exp2f(m_i - mnew);
    const bool mchg = mnew > m_i;
    m_i = mnew;
    float rs = 0.f;
#pragma unroll
    for (int nk = 0; nk < 8; ++nk)
#pragma unroll
      for (int r = 0; r < 4; ++r) {
        const float pe = exp2f(fmaf(s[nk][r], sc, -mnew));
        s[nk][r] = pe;
        rs += pe;
      }
    rs += __shfl_xor(rs, 16, 64);
    rs += __shfl_xor(rs, 32, 64);
    l_i = l_i * alpha + rs;
    if (__any(mchg)) {
#pragma unroll
      for (int r = 0; r < 4; ++r) {
        const float ar = __shfl(alpha, q4 * 4 + r, 64);
#pragma unroll
        for (int d4 = 0; d4 < 4; ++d4) o[d4][r] *= ar;
      }
    }
    // --- P write (wave-private; same-wave DS ops are in-order, no barrier) ---
#pragma unroll
    for (int nk = 0; nk < 8; ++nk) {
      union { __hip_bfloat162 h2; uint32_t u; } c01, c23;
      c01.h2 = __float22bfloat162_rn(make_float2(s[nk][0], s[nk][1]));
      c23.h2 = __float22bfloat162_rn(make_float2(s[nk][2], s[nk][3]));
      uint2 pkw; pkw.x = c01.u; pkw.y = c23.u;
      *(uint2*)&Pw[l16 * 136 + nk * 16 + q4 * 4] = pkw;
    }
    // --- O += P·V ---
#pragma unroll
    for (int ks = 0; ks < 4; ++ks) {
      const bf16x8 pf = *(const bf16x8*)&Pw[l16 * 136 + ks * 32 + q4 * 8];
#pragma unroll
      for (int d4 = 0; d4 < 4; ++d4) {
        const int d = d4 * 16 + l16;
        const int col = (ks * 32 + q4 * 8 + 16 * (d >> 3)) & 127;
        const bf16x8 vf = *(const bf16x8*)&Vt[d * 136 + col];
        o[d4] = __builtin_amdgcn_mfma_f32_16x16x32_bf16(pf, vf, o[d4], 0, 0, 0);
      }
    }
    // --- strip boundary: write O, reset state, switch to strip 1 ---
    if (lastOfStrip) {
      const float linv = 1.0f / l_i;
#pragma unroll
      for (int r = 0; r < 4; ++r) {
        const float lr = __shfl(linv, q4 * 4 + r, 64);
        const int q = qb * 64 + wave * 16 + q4 * 4 + r;
        const size_t rowoff = obase + (size_t)q * C + hD;
#pragma unroll
        for (int d4 = 0; d4 < 4; ++d4)
          attn[rowoff + d4 * 16 + l16] = f2b(o[d4][r] * lr);
      }
      if (!ss1) {
        ss1 = true;
        qb = qb1;
        qrow = qb * 64 + wave * 16 + l16;
        qf0 = *(const bf16x8*)&kqv[base + (size_t)qrow * C3 + C + hD + q4 * 8];
        qf1 = *(const bf16x8*)&kqv[base + (size_t)qrow * C3 + C + hD + 32 + q4 * 8];
#pragma unroll
        for (int d4 = 0; d4 < 4; ++d4) o[d4] = (f32x4){0.f, 0.f, 0.f, 0.f};
        m_i = -1e30f; l_i = 0.f;
        kt = 0;
      }
    } else {
      ++kt;
    }
  }
}

extern "C" void kernel_launch(void* const* d_in, const int* in_sizes, int n_in,
                              void* d_out, int out_size, void* d_ws, size_t ws_size,
                              hipStream_t stream) {
  const float* x      = (const float*)d_in[0];  // (2,2048,1024) fp32
  const float* w_attn = (const float*)d_in[1];  // (3072,1024)  fp32
  const float* b_attn = (const float*)d_in[2];  // (3072,)      fp32
  const float* w_proj = (const float*)d_in[3];  // (1024,1024)  fp32
  const float* b_proj = (const float*)d_in[4];  // (1024,)      fp32
  float* out = (float*)d_out;                   // (2,2048,1024) fp32

  // ws layout (bf16): xb | wab | wpb | kqv | attnb
  uint16_t* xb    = (uint16_t*)d_ws;                     // 4096*1024
  uint16_t* wab   = xb  + (size_t)4096 * 1024;           // 3072*1024
  uint16_t* wpb   = wab + (size_t)3072 * 1024;           // 1024*1024
  uint16_t* kqv   = wpb + (size_t)1024 * 1024;           // 4096*3072
  uint16_t* attnb = kqv + (size_t)4096 * 3072;           // 4096*1024

  dim3 blk(256, 1, 1);
  hipLaunchKernelGGL(cvt_all, dim3(8192), blk, 0, stream, x, w_attn, w_proj, xb, wab, wpb);

  hipLaunchKernelGGL((gemm_bt_bias<128, true>), dim3(3072 / 128, 4096 / 128, 1), blk, 0, stream,
                     xb, wab, b_attn, (void*)kqv, 4096, 3072, 1024);
  hipLaunchKernelGGL(attn_flash, dim3(512, 1, 1), blk, 0, stream, kqv, attnb);
  hipLaunchKernelGGL((gemm_bt_bias<64, false>), dim3(1024 / 128, 4096 / 64, 1), blk, 0, stream,
                     attnb, wpb, b_proj, (void*)out, 4096, 1024, 1024);
}